// Round 2
// baseline (1591.335 us; speedup 1.0000x reference)
//
#include <hip/hip_runtime.h>
#include <hip/hip_bf16.h>

// MHSA_69621419869026 — p=4 sketch linear attention, MI355X gfx950.
// Round 1: same structure as round 0, but ALL I/O is fp32 (reference dtypes).
// Dims: B=4 S=8192 D=512 H=8 HD=R=64, N=B*S=32768.
// Workspace layout (floats), total ~219 MB (validated: round-1 run touched it
// all without faulting):
//   Q   [32][8192][64]  (overwritten in-place by phi_q)
//   K   [32][8192][64]  (overwritten by phi_k, then reused as out_attn [N,512])
//   V   [32][8192][64]
//   KVP [32][32][64][64] partial kv,  KSP [32][32][64] partial ksum
//   KV  [32][64][64],    KS [32][64]

#define SEQ 8192

// ---------------- QKV projection: q/k/v = gamma*(x@W + b) + beta -------------
// grid (512, 8, 3): n-tile 64, head (j-tile 64), z = q/k/v. block 256.
__global__ __launch_bounds__(256) void gemm_qkv(
    const float* __restrict__ x,
    const float* __restrict__ Wq, const float* __restrict__ Wk,
    const float* __restrict__ Wv,
    const float* __restrict__ bq, const float* __restrict__ bk,
    const float* __restrict__ bvp,
    const float* __restrict__ gq, const float* __restrict__ bbq,
    const float* __restrict__ gk, const float* __restrict__ bbk,
    float* __restrict__ Q, float* __restrict__ Ko, float* __restrict__ Vo)
{
    const int z = blockIdx.z;
    const float* W    = (z == 0) ? Wq : (z == 1) ? Wk : Wv;
    const float* bias = (z == 0) ? bq : (z == 1) ? bk : bvp;
    float* C = (z == 0) ? Q : (z == 1) ? Ko : Vo;
    float g = 1.0f, be = 0.0f;
    if (z == 0)      { g = gq[0]; be = bbq[0]; }
    else if (z == 1) { g = gk[0]; be = bbk[0]; }

    __shared__ float As[16][68];   // As[kk][row]  (A transposed in LDS)
    __shared__ float Bs[16][68];   // Bs[kk][col]
    const int tid = threadIdx.x;
    const int tx = tid & 15, ty = tid >> 4;
    const int n0 = blockIdx.x * 64;
    const int j0 = blockIdx.y * 64;
    const int arow = tid >> 2,  akk  = (tid & 3) * 4;
    const int bkk  = tid >> 4,  bcol = (tid & 15) * 4;
    float acc[4][4] = {};

    for (int k0 = 0; k0 < 512; k0 += 16) {
        float4 av  = *(const float4*)&x[(size_t)(n0 + arow) * 512 + k0 + akk];
        float4 bv4 = *(const float4*)&W[(size_t)(k0 + bkk) * 512 + j0 + bcol];
        __syncthreads();
        As[akk + 0][arow] = av.x;  As[akk + 1][arow] = av.y;
        As[akk + 2][arow] = av.z;  As[akk + 3][arow] = av.w;
        Bs[bkk][bcol + 0] = bv4.x; Bs[bkk][bcol + 1] = bv4.y;
        Bs[bkk][bcol + 2] = bv4.z; Bs[bkk][bcol + 3] = bv4.w;
        __syncthreads();
        #pragma unroll
        for (int kk = 0; kk < 16; ++kk) {
            float4 a = *(const float4*)&As[kk][ty * 4];
            float4 b = *(const float4*)&Bs[kk][tx * 4];
            acc[0][0] = fmaf(a.x, b.x, acc[0][0]); acc[0][1] = fmaf(a.x, b.y, acc[0][1]);
            acc[0][2] = fmaf(a.x, b.z, acc[0][2]); acc[0][3] = fmaf(a.x, b.w, acc[0][3]);
            acc[1][0] = fmaf(a.y, b.x, acc[1][0]); acc[1][1] = fmaf(a.y, b.y, acc[1][1]);
            acc[1][2] = fmaf(a.y, b.z, acc[1][2]); acc[1][3] = fmaf(a.y, b.w, acc[1][3]);
            acc[2][0] = fmaf(a.z, b.x, acc[2][0]); acc[2][1] = fmaf(a.z, b.y, acc[2][1]);
            acc[2][2] = fmaf(a.z, b.z, acc[2][2]); acc[2][3] = fmaf(a.z, b.w, acc[2][3]);
            acc[3][0] = fmaf(a.w, b.x, acc[3][0]); acc[3][1] = fmaf(a.w, b.y, acc[3][1]);
            acc[3][2] = fmaf(a.w, b.z, acc[3][2]); acc[3][3] = fmaf(a.w, b.w, acc[3][3]);
        }
    }
    // epilogue: write [bh][s][hd] layout, apply bias/gamma/beta
    const int bidx = n0 >> 13;            // n0/8192 (tiles never straddle b)
    const int head = blockIdx.y;
    #pragma unroll
    for (int i = 0; i < 4; ++i) {
        const int n = n0 + ty * 4 + i;
        const int s = n & (SEQ - 1);
        float4 o;
        o.x = fmaf(g, acc[i][0] + bias[j0 + tx * 4 + 0], be);
        o.y = fmaf(g, acc[i][1] + bias[j0 + tx * 4 + 1], be);
        o.z = fmaf(g, acc[i][2] + bias[j0 + tx * 4 + 2], be);
        o.w = fmaf(g, acc[i][3] + bias[j0 + tx * 4 + 3], be);
        *(float4*)&C[((size_t)(bidx * 8 + head) * SEQ + s) * 64 + tx * 4] = o;
    }
}

// ---------------- sketch: phi = (0.125 * (z@G1) * (z@G2))^2, in place --------
// grid 4096 (64 rows/block), block 256 = (r=64, rowgrp=4)
__global__ __launch_bounds__(256) void sketch_p4(
    float* __restrict__ Z,
    const float* __restrict__ G1, const float* __restrict__ G2)
{
    __shared__ float G1s[64][65];
    __shared__ float G2s[64][65];
    __shared__ float zs[4][68];
    const int tid = threadIdx.x;
    for (int i = tid; i < 4096; i += 256) {
        G1s[i >> 6][i & 63] = G1[i];
        G2s[i >> 6][i & 63] = G2[i];
    }
    const int tx = tid & 63, ty = tid >> 6;
    const size_t base = (size_t)blockIdx.x * 64;
    for (int it = 0; it < 16; ++it) {
        __syncthreads();
        zs[ty][tx] = Z[(base + it * 4 + ty) * 64 + tx];
        __syncthreads();
        float u = 0.f, w = 0.f;
        #pragma unroll
        for (int i = 0; i < 64; ++i) {
            float zv = zs[ty][i];
            u = fmaf(zv, G1s[i][tx], u);
            w = fmaf(zv, G2s[i][tx], w);
        }
        float h = 0.125f * u * w;
        Z[(base + it * 4 + ty) * 64 + tx] = h * h;
    }
}

// ---------------- kv = phi_k^T @ v, ksum = sum_s phi_k (split-S partials) ----
// grid (32 bh, 32 chunks of 256 s). block 256: thread = (r = tid>>2, hd-quarter)
__global__ __launch_bounds__(256) void kv_partial(
    const float* __restrict__ PHIK, const float* __restrict__ V,
    float* __restrict__ KVP, float* __restrict__ KSP)
{
    const int bh = blockIdx.x, ch = blockIdx.y;
    const float* phik = PHIK + ((size_t)bh * SEQ + ch * 256) * 64;
    const float* v    = V    + ((size_t)bh * SEQ + ch * 256) * 64;
    __shared__ float ps[64][65];
    __shared__ float vs[64][65];
    const int tid = threadIdx.x;
    const int r = tid >> 2, q4 = (tid & 3) * 16;
    float acc[16] = {};
    float ks = 0.f;
    for (int sub = 0; sub < 4; ++sub) {
        __syncthreads();
        for (int i = tid; i < 4096; i += 256) {
            ps[i >> 6][i & 63] = phik[sub * 4096 + i];
            vs[i >> 6][i & 63] = v[sub * 4096 + i];
        }
        __syncthreads();
        for (int s = 0; s < 64; ++s) {
            float p = ps[s][r];
            ks += p;
            #pragma unroll
            for (int i = 0; i < 16; ++i) acc[i] = fmaf(p, vs[s][q4 + i], acc[i]);
        }
    }
    float* kvp = KVP + ((size_t)(bh * 32 + ch) * 64 + r) * 64 + q4;
    #pragma unroll
    for (int i = 0; i < 16; ++i) kvp[i] = acc[i];
    if ((tid & 3) == 0) KSP[(bh * 32 + ch) * 64 + r] = ks;
}

__global__ __launch_bounds__(256) void kv_reduce(
    const float* __restrict__ KVP, const float* __restrict__ KSP,
    float* __restrict__ KV, float* __restrict__ KS)
{
    const int bh = blockIdx.x, tid = threadIdx.x;
    for (int e = tid; e < 4096; e += 256) {
        float s = 0.f;
        for (int c = 0; c < 32; ++c) s += KVP[(size_t)(bh * 32 + c) * 4096 + e];
        KV[(size_t)bh * 4096 + e] = s;
    }
    if (tid < 64) {
        float s = 0.f;
        for (int c = 0; c < 32; ++c) s += KSP[(bh * 32 + c) * 64 + tid];
        KS[bh * 64 + tid] = s;
    }
}

// ---------------- out_attn = (phi_q @ kv) / (phi_q @ ksum + eps) -------------
// grid (32 bh, 64 chunks of 128 s). Writes [b][s][h][hd] = [N,512] layout.
__global__ __launch_bounds__(256) void attn_out(
    const float* __restrict__ PHIQ, const float* __restrict__ KV,
    const float* __restrict__ KS, float* __restrict__ OA)
{
    const int bh = blockIdx.x;
    const int b = bh >> 3, h = bh & 7;
    __shared__ float kvs[64][65];
    __shared__ float kss[64];
    __shared__ float pqs[4][68];
    const int tid = threadIdx.x;
    const int tx = tid & 63, ty = tid >> 6;
    for (int i = tid; i < 4096; i += 256) kvs[i >> 6][i & 63] = KV[(size_t)bh * 4096 + i];
    if (tid < 64) kss[tid] = KS[bh * 64 + tid];
    const int s0 = blockIdx.y * 128;
    for (int it = 0; it < 32; ++it) {
        const int srow = s0 + it * 4;
        __syncthreads();
        pqs[ty][tx] = PHIQ[((size_t)bh * SEQ + srow + ty) * 64 + tx];
        __syncthreads();
        float num = 0.f, den = 1e-6f;   // EPS folded into init
        #pragma unroll
        for (int r = 0; r < 64; ++r) {
            float p = pqs[ty][r];
            num = fmaf(p, kvs[r][tx], num);
            den = fmaf(p, kss[r], den);
        }
        const int s = srow + ty;
        OA[((size_t)(b * SEQ + s) * 8 + h) * 64 + tx] = num / den;
    }
}

// ---------------- final projection: out = OA @ Wp + bp (fp32 out) ------------
__global__ __launch_bounds__(256) void gemm_final(
    const float* __restrict__ A, const float* __restrict__ W,
    const float* __restrict__ bias, float* __restrict__ out)
{
    __shared__ float As[16][68];
    __shared__ float Bs[16][68];
    const int tid = threadIdx.x;
    const int tx = tid & 15, ty = tid >> 4;
    const int n0 = blockIdx.x * 64;
    const int j0 = blockIdx.y * 64;
    const int arow = tid >> 2,  akk  = (tid & 3) * 4;
    const int bkk  = tid >> 4,  bcol = (tid & 15) * 4;
    float acc[4][4] = {};

    for (int k0 = 0; k0 < 512; k0 += 16) {
        float4 av  = *(const float4*)&A[(size_t)(n0 + arow) * 512 + k0 + akk];
        float4 bv4 = *(const float4*)&W[(size_t)(k0 + bkk) * 512 + j0 + bcol];
        __syncthreads();
        As[akk + 0][arow] = av.x;  As[akk + 1][arow] = av.y;
        As[akk + 2][arow] = av.z;  As[akk + 3][arow] = av.w;
        Bs[bkk][bcol + 0] = bv4.x; Bs[bkk][bcol + 1] = bv4.y;
        Bs[bkk][bcol + 2] = bv4.z; Bs[bkk][bcol + 3] = bv4.w;
        __syncthreads();
        #pragma unroll
        for (int kk = 0; kk < 16; ++kk) {
            float4 a = *(const float4*)&As[kk][ty * 4];
            float4 b = *(const float4*)&Bs[kk][tx * 4];
            acc[0][0] = fmaf(a.x, b.x, acc[0][0]); acc[0][1] = fmaf(a.x, b.y, acc[0][1]);
            acc[0][2] = fmaf(a.x, b.z, acc[0][2]); acc[0][3] = fmaf(a.x, b.w, acc[0][3]);
            acc[1][0] = fmaf(a.y, b.x, acc[1][0]); acc[1][1] = fmaf(a.y, b.y, acc[1][1]);
            acc[1][2] = fmaf(a.y, b.z, acc[1][2]); acc[1][3] = fmaf(a.y, b.w, acc[1][3]);
            acc[2][0] = fmaf(a.z, b.x, acc[2][0]); acc[2][1] = fmaf(a.z, b.y, acc[2][1]);
            acc[2][2] = fmaf(a.z, b.z, acc[2][2]); acc[2][3] = fmaf(a.z, b.w, acc[2][3]);
            acc[3][0] = fmaf(a.w, b.x, acc[3][0]); acc[3][1] = fmaf(a.w, b.y, acc[3][1]);
            acc[3][2] = fmaf(a.w, b.z, acc[3][2]); acc[3][3] = fmaf(a.w, b.w, acc[3][3]);
        }
    }
    #pragma unroll
    for (int i = 0; i < 4; ++i) {
        const int n = n0 + ty * 4 + i;
        float4 o;
        o.x = acc[i][0] + bias[j0 + tx * 4 + 0];
        o.y = acc[i][1] + bias[j0 + tx * 4 + 1];
        o.z = acc[i][2] + bias[j0 + tx * 4 + 2];
        o.w = acc[i][3] + bias[j0 + tx * 4 + 3];
        *(float4*)&out[(size_t)n * 512 + j0 + tx * 4] = o;
    }
}

extern "C" void kernel_launch(void* const* d_in, const int* in_sizes, int n_in,
                              void* d_out, int out_size, void* d_ws, size_t ws_size,
                              hipStream_t stream)
{
    (void)in_sizes; (void)n_in; (void)out_size; (void)ws_size;
    const float* x   = (const float*)d_in[0];
    const float* Wq  = (const float*)d_in[1];
    const float* bq  = (const float*)d_in[2];
    const float* Wk  = (const float*)d_in[3];
    const float* bk  = (const float*)d_in[4];
    const float* Wv  = (const float*)d_in[5];
    const float* bv  = (const float*)d_in[6];
    const float* Wp  = (const float*)d_in[7];
    const float* bp  = (const float*)d_in[8];
    const float* gq  = (const float*)d_in[9];
    const float* bbq = (const float*)d_in[10];
    const float* gk  = (const float*)d_in[11];
    const float* bbk = (const float*)d_in[12];
    const float* qG1 = (const float*)d_in[13];
    const float* qG2 = (const float*)d_in[14];
    const float* kG1 = (const float*)d_in[15];
    const float* kG2 = (const float*)d_in[16];

    float* ws  = (float*)d_ws;
    float* Q   = ws;                      // 16777216 f
    float* Kb  = ws + 16777216;           // 16777216 f (phi_k, later out_attn)
    float* V   = ws + 2 * 16777216;       // 16777216 f
    float* KVP = ws + 3 * 16777216;       // 4194304 f
    float* KSP = KVP + 4194304;           // 65536 f
    float* KV  = KSP + 65536;             // 131072 f
    float* KS  = KV + 131072;             // 2048 f   (total ~219 MB)
    float* out = (float*)d_out;

    hipLaunchKernelGGL(gemm_qkv, dim3(512, 8, 3), dim3(256), 0, stream,
                       x, Wq, Wk, Wv, bq, bk, bv, gq, bbq, gk, bbk, Q, Kb, V);
    hipLaunchKernelGGL(sketch_p4, dim3(4096), dim3(256), 0, stream, Q, qG1, qG2);
    hipLaunchKernelGGL(sketch_p4, dim3(4096), dim3(256), 0, stream, Kb, kG1, kG2);
    hipLaunchKernelGGL(kv_partial, dim3(32, 32), dim3(256), 0, stream, Kb, V, KVP, KSP);
    hipLaunchKernelGGL(kv_reduce, dim3(32), dim3(256), 0, stream, KVP, KSP, KV, KS);
    hipLaunchKernelGGL(attn_out, dim3(32, 64), dim3(256), 0, stream, Q, KV, KS, Kb);
    hipLaunchKernelGGL(gemm_final, dim3(512, 8), dim3(256), 0, stream, Kb, Wp, bp, out);
}

// Round 3
// 846.310 us; speedup vs baseline: 1.8803x; 1.8803x over previous
//
#include <hip/hip_runtime.h>
#include <hip/hip_bf16.h>

// MHSA_69621419869026 — p=4 sketch linear attention, MI355X gfx950.
// Round 2: QKV + final projection GEMMs moved to bf16 MFMA (16x16x32),
// m97-style 128x128 tile with global_load_lds(16B). Sketch/kv/attn still fp32.
// Dims: B=4 S=8192 D=512 H=8 HD=R=64, N=B*S=32768.
//
// Workspace (floats unless noted), ~238 MB:
//   Q    [32][8192][64] f32   (overwritten in-place by phi_q)
//   Kb   [32][8192][64] f32   (overwritten by phi_k)
//   V    [32][8192][64] f32
//   R3   32 MB region, time-shared: xb bf16[32768][512] -> KVP/KSP -> OAb bf16
//   KV   [32][64][64] f32, KS [32][64] f32
//   WT   bf16 [4][512][512]  (W^T, j-major: WT[z][j][k])

#define SEQ 8192

typedef __attribute__((ext_vector_type(8))) short bf16x8;
typedef __attribute__((ext_vector_type(4))) float f32x4;

__device__ __forceinline__ unsigned short f2b(float f) {
    union { float f; unsigned int i; } v; v.f = f;
    unsigned int r = v.i + 0x7fffu + ((v.i >> 16) & 1u);   // RNE
    return (unsigned short)(r >> 16);
}

#if __has_builtin(__builtin_amdgcn_global_load_lds)
#define ASYNC_CP 1
#endif

__device__ __forceinline__ void cp16(const unsigned short* g, unsigned short* l) {
#ifdef ASYNC_CP
    __builtin_amdgcn_global_load_lds(
        (const __attribute__((address_space(1))) unsigned int*)g,
        (__attribute__((address_space(3))) unsigned int*)l, 16, 0, 0);
#endif
}

// ---------------- pre-pass: x fp32 -> bf16 (RNE) ----------------------------
__global__ __launch_bounds__(256) void convert_x(
    const float* __restrict__ x, unsigned short* __restrict__ xb)
{
    size_t i = ((size_t)blockIdx.x * 256 + threadIdx.x) * 8;
    float4 a = *(const float4*)&x[i];
    float4 b = *(const float4*)&x[i + 4];
    ushort4 o1 = { f2b(a.x), f2b(a.y), f2b(a.z), f2b(a.w) };
    ushort4 o2 = { f2b(b.x), f2b(b.y), f2b(b.z), f2b(b.w) };
    *(ushort4*)&xb[i]     = o1;
    *(ushort4*)&xb[i + 4] = o2;
}

// ---------------- pre-pass: W fp32 [k][n] -> WT bf16 [n][k] ------------------
// grid (16,16,4) block 256
__global__ __launch_bounds__(256) void convert_wT(
    const float* __restrict__ Wq, const float* __restrict__ Wk,
    const float* __restrict__ Wv, const float* __restrict__ Wp,
    unsigned short* __restrict__ WT)
{
    const int z = blockIdx.z;
    const float* W = (z == 0) ? Wq : (z == 1) ? Wk : (z == 2) ? Wv : Wp;
    unsigned short* O = WT + (size_t)z * 262144;
    __shared__ float t[32][33];
    const int tid = threadIdx.x;
    const int tx = tid & 31, ty = tid >> 5;          // ty 0..7
    const int k0 = blockIdx.x * 32, n0 = blockIdx.y * 32;
    #pragma unroll
    for (int i = 0; i < 4; ++i)
        t[ty + 8 * i][tx] = W[(size_t)(k0 + ty + 8 * i) * 512 + n0 + tx];
    __syncthreads();
    #pragma unroll
    for (int i = 0; i < 4; ++i)
        O[(size_t)(n0 + ty + 8 * i) * 512 + k0 + tx] = f2b(t[tx][ty + 8 * i]);
}

// ---------------- bf16 MFMA GEMM: QKV projection -----------------------------
// grid (256 token-tiles, 4 j-tiles, 3 z). block 256 = 4 waves, 128x128 tile.
// C written to [bh][s][hd] f32 with gamma*(.+bias)+beta fused.
__global__ __launch_bounds__(256) void gemm_mfma_qkv(
    const unsigned short* __restrict__ xb,   // [32768][512] bf16
    const unsigned short* __restrict__ WT,   // [3][512][512] bf16 (j-major)
    const float* __restrict__ bq, const float* __restrict__ bk,
    const float* __restrict__ bvp,
    const float* __restrict__ gq, const float* __restrict__ bbq,
    const float* __restrict__ gk, const float* __restrict__ bbk,
    float* __restrict__ Q, float* __restrict__ Ko, float* __restrict__ Vo)
{
    const int z = blockIdx.z;
    const unsigned short* Wt = WT + (size_t)z * 262144;
    const float* bias = (z == 0) ? bq : (z == 1) ? bk : bvp;
    float g = 1.0f, be = 0.0f;
    if (z == 0)      { g = gq[0]; be = bbq[0]; }
    else if (z == 1) { g = gk[0]; be = bbk[0]; }
    float* C = (z == 0) ? Q : (z == 1) ? Ko : Vo;

    __shared__ __align__(16) unsigned short As[128 * 32];
    __shared__ __align__(16) unsigned short Bs[128 * 32];

    const int tid = threadIdx.x;
    const int w = tid >> 6, lane = tid & 63;
    const int n0 = blockIdx.x * 128;   // token tile
    const int j0 = blockIdx.y * 128;   // feature tile
    const int wr = w >> 1, wc = w & 1;

    // staging: wave w stages rows [w*32, w*32+32) of both tiles, 2 calls each
    const int r0 = w * 32 + (lane >> 2);
    const int kq = (lane & 3) * 8;
    const unsigned short* gA = &xb[(size_t)(n0 + r0) * 512 + kq];
    const unsigned short* gB = &Wt[(size_t)(j0 + r0) * 512 + kq];
    unsigned short* lA = &As[(w * 32) * 32];
    unsigned short* lB = &Bs[(w * 32) * 32];

    f32x4 acc[4][4];
    #pragma unroll
    for (int i = 0; i < 4; ++i)
        #pragma unroll
        for (int j = 0; j < 4; ++j) { acc[i][j] = (f32x4){0.f, 0.f, 0.f, 0.f}; }

    for (int k0 = 0; k0 < 512; k0 += 32) {
        __syncthreads();
#ifdef ASYNC_CP
        cp16(gA + k0, lA);
        cp16(gA + 16 * 512 + k0, lA + 16 * 32);
        cp16(gB + k0, lB);
        cp16(gB + 16 * 512 + k0, lB + 16 * 32);
#else
        { uint4 v = *(const uint4*)(gA + k0);            *(uint4*)(lA + (size_t)lane * 8) = v; }
        { uint4 v = *(const uint4*)(gA + 16 * 512 + k0); *(uint4*)(lA + 16 * 32 + (size_t)lane * 8) = v; }
        { uint4 v = *(const uint4*)(gB + k0);            *(uint4*)(lB + (size_t)lane * 8) = v; }
        { uint4 v = *(const uint4*)(gB + 16 * 512 + k0); *(uint4*)(lB + 16 * 32 + (size_t)lane * 8) = v; }
#endif
        __syncthreads();

        bf16x8 af[4], bfr[4];
        #pragma unroll
        for (int i = 0; i < 4; ++i) {
            af[i]  = *(const bf16x8*)&As[(wr * 64 + i * 16 + (lane & 15)) * 32 + (lane >> 4) * 8];
            bfr[i] = *(const bf16x8*)&Bs[(wc * 64 + i * 16 + (lane & 15)) * 32 + (lane >> 4) * 8];
        }
        #pragma unroll
        for (int mi = 0; mi < 4; ++mi)
            #pragma unroll
            for (int ni = 0; ni < 4; ++ni)
                acc[mi][ni] = __builtin_amdgcn_mfma_f32_16x16x32_bf16(
                    af[mi], bfr[ni], acc[mi][ni], 0, 0, 0);
    }

    // epilogue: C/D mapping col=lane&15, row=(lane>>4)*4+reg
    #pragma unroll
    for (int ni = 0; ni < 4; ++ni) {
        const int jcol = j0 + wc * 64 + ni * 16 + (lane & 15);
        const float bv = bias[jcol];
        const int h = jcol >> 6, hd = jcol & 63;
        #pragma unroll
        for (int mi = 0; mi < 4; ++mi) {
            #pragma unroll
            for (int r = 0; r < 4; ++r) {
                const int t = n0 + wr * 64 + mi * 16 + (lane >> 4) * 4 + r;
                const int b = t >> 13, s = t & (SEQ - 1);
                C[(((size_t)(b * 8 + h)) * SEQ + s) * 64 + hd] =
                    fmaf(g, acc[mi][ni][r] + bv, be);
            }
        }
    }
}

// ---------------- bf16 MFMA GEMM: final projection ---------------------------
// grid (256, 4). A = OAb bf16 [32768][512], B = WT[3]. out fp32 [32768][512].
__global__ __launch_bounds__(256) void gemm_mfma_final(
    const unsigned short* __restrict__ Ab,
    const unsigned short* __restrict__ WTp,   // already offset to Wp^T
    const float* __restrict__ bias, float* __restrict__ out)
{
    __shared__ __align__(16) unsigned short As[128 * 32];
    __shared__ __align__(16) unsigned short Bs[128 * 32];

    const int tid = threadIdx.x;
    const int w = tid >> 6, lane = tid & 63;
    const int n0 = blockIdx.x * 128;
    const int j0 = blockIdx.y * 128;
    const int wr = w >> 1, wc = w & 1;

    const int r0 = w * 32 + (lane >> 2);
    const int kq = (lane & 3) * 8;
    const unsigned short* gA = &Ab[(size_t)(n0 + r0) * 512 + kq];
    const unsigned short* gB = &WTp[(size_t)(j0 + r0) * 512 + kq];
    unsigned short* lA = &As[(w * 32) * 32];
    unsigned short* lB = &Bs[(w * 32) * 32];

    f32x4 acc[4][4];
    #pragma unroll
    for (int i = 0; i < 4; ++i)
        #pragma unroll
        for (int j = 0; j < 4; ++j) { acc[i][j] = (f32x4){0.f, 0.f, 0.f, 0.f}; }

    for (int k0 = 0; k0 < 512; k0 += 32) {
        __syncthreads();
#ifdef ASYNC_CP
        cp16(gA + k0, lA);
        cp16(gA + 16 * 512 + k0, lA + 16 * 32);
        cp16(gB + k0, lB);
        cp16(gB + 16 * 512 + k0, lB + 16 * 32);
#else
        { uint4 v = *(const uint4*)(gA + k0);            *(uint4*)(lA + (size_t)lane * 8) = v; }
        { uint4 v = *(const uint4*)(gA + 16 * 512 + k0); *(uint4*)(lA + 16 * 32 + (size_t)lane * 8) = v; }
        { uint4 v = *(const uint4*)(gB + k0);            *(uint4*)(lB + (size_t)lane * 8) = v; }
        { uint4 v = *(const uint4*)(gB + 16 * 512 + k0); *(uint4*)(lB + 16 * 32 + (size_t)lane * 8) = v; }
#endif
        __syncthreads();

        bf16x8 af[4], bfr[4];
        #pragma unroll
        for (int i = 0; i < 4; ++i) {
            af[i]  = *(const bf16x8*)&As[(wr * 64 + i * 16 + (lane & 15)) * 32 + (lane >> 4) * 8];
            bfr[i] = *(const bf16x8*)&Bs[(wc * 64 + i * 16 + (lane & 15)) * 32 + (lane >> 4) * 8];
        }
        #pragma unroll
        for (int mi = 0; mi < 4; ++mi)
            #pragma unroll
            for (int ni = 0; ni < 4; ++ni)
                acc[mi][ni] = __builtin_amdgcn_mfma_f32_16x16x32_bf16(
                    af[mi], bfr[ni], acc[mi][ni], 0, 0, 0);
    }

    #pragma unroll
    for (int ni = 0; ni < 4; ++ni) {
        const int jcol = j0 + wc * 64 + ni * 16 + (lane & 15);
        const float bv = bias[jcol];
        #pragma unroll
        for (int mi = 0; mi < 4; ++mi) {
            #pragma unroll
            for (int r = 0; r < 4; ++r) {
                const int t = n0 + wr * 64 + mi * 16 + (lane >> 4) * 4 + r;
                out[(size_t)t * 512 + jcol] = acc[mi][ni][r] + bv;
            }
        }
    }
}

// ---------------- sketch: phi = (0.125 * (z@G1) * (z@G2))^2, in place --------
__global__ __launch_bounds__(256) void sketch_p4(
    float* __restrict__ Z,
    const float* __restrict__ G1, const float* __restrict__ G2)
{
    __shared__ float G1s[64][65];
    __shared__ float G2s[64][65];
    __shared__ float zs[4][68];
    const int tid = threadIdx.x;
    for (int i = tid; i < 4096; i += 256) {
        G1s[i >> 6][i & 63] = G1[i];
        G2s[i >> 6][i & 63] = G2[i];
    }
    const int tx = tid & 63, ty = tid >> 6;
    const size_t base = (size_t)blockIdx.x * 64;
    for (int it = 0; it < 16; ++it) {
        __syncthreads();
        zs[ty][tx] = Z[(base + it * 4 + ty) * 64 + tx];
        __syncthreads();
        float u = 0.f, w = 0.f;
        #pragma unroll
        for (int i = 0; i < 64; ++i) {
            float zv = zs[ty][i];
            u = fmaf(zv, G1s[i][tx], u);
            w = fmaf(zv, G2s[i][tx], w);
        }
        float h = 0.125f * u * w;
        Z[(base + it * 4 + ty) * 64 + tx] = h * h;
    }
}

// ---------------- kv = phi_k^T @ v, ksum (split-S partials) ------------------
__global__ __launch_bounds__(256) void kv_partial(
    const float* __restrict__ PHIK, const float* __restrict__ V,
    float* __restrict__ KVP, float* __restrict__ KSP)
{
    const int bh = blockIdx.x, ch = blockIdx.y;
    const float* phik = PHIK + ((size_t)bh * SEQ + ch * 256) * 64;
    const float* v    = V    + ((size_t)bh * SEQ + ch * 256) * 64;
    __shared__ float ps[64][65];
    __shared__ float vs[64][65];
    const int tid = threadIdx.x;
    const int r = tid >> 2, q4 = (tid & 3) * 16;
    float acc[16] = {};
    float ks = 0.f;
    for (int sub = 0; sub < 4; ++sub) {
        __syncthreads();
        for (int i = tid; i < 4096; i += 256) {
            ps[i >> 6][i & 63] = phik[sub * 4096 + i];
            vs[i >> 6][i & 63] = v[sub * 4096 + i];
        }
        __syncthreads();
        for (int s = 0; s < 64; ++s) {
            float p = ps[s][r];
            ks += p;
            #pragma unroll
            for (int i = 0; i < 16; ++i) acc[i] = fmaf(p, vs[s][q4 + i], acc[i]);
        }
    }
    float* kvp = KVP + ((size_t)(bh * 32 + ch) * 64 + r) * 64 + q4;
    #pragma unroll
    for (int i = 0; i < 16; ++i) kvp[i] = acc[i];
    if ((tid & 3) == 0) KSP[(bh * 32 + ch) * 64 + r] = ks;
}

__global__ __launch_bounds__(256) void kv_reduce(
    const float* __restrict__ KVP, const float* __restrict__ KSP,
    float* __restrict__ KV, float* __restrict__ KS)
{
    const int bh = blockIdx.x, tid = threadIdx.x;
    for (int e = tid; e < 4096; e += 256) {
        float s = 0.f;
        for (int c = 0; c < 32; ++c) s += KVP[(size_t)(bh * 32 + c) * 4096 + e];
        KV[(size_t)bh * 4096 + e] = s;
    }
    if (tid < 64) {
        float s = 0.f;
        for (int c = 0; c < 32; ++c) s += KSP[(bh * 32 + c) * 64 + tid];
        KS[bh * 64 + tid] = s;
    }
}

// ---------------- out_attn -> bf16 [t][h*64+hd] ------------------------------
__global__ __launch_bounds__(256) void attn_out(
    const float* __restrict__ PHIQ, const float* __restrict__ KV,
    const float* __restrict__ KS, unsigned short* __restrict__ OAb)
{
    const int bh = blockIdx.x;
    const int b = bh >> 3, h = bh & 7;
    __shared__ float kvs[64][65];
    __shared__ float kss[64];
    __shared__ float pqs[4][68];
    const int tid = threadIdx.x;
    const int tx = tid & 63, ty = tid >> 6;
    for (int i = tid; i < 4096; i += 256) kvs[i >> 6][i & 63] = KV[(size_t)bh * 4096 + i];
    if (tid < 64) kss[tid] = KS[bh * 64 + tid];
    const int s0 = blockIdx.y * 128;
    for (int it = 0; it < 32; ++it) {
        const int srow = s0 + it * 4;
        __syncthreads();
        pqs[ty][tx] = PHIQ[((size_t)bh * SEQ + srow + ty) * 64 + tx];
        __syncthreads();
        float num = 0.f, den = 1e-6f;
        #pragma unroll
        for (int r = 0; r < 64; ++r) {
            float p = pqs[ty][r];
            num = fmaf(p, kvs[r][tx], num);
            den = fmaf(p, kss[r], den);
        }
        const int s = srow + ty;
        OAb[((size_t)(b * SEQ + s)) * 512 + h * 64 + tx] = f2b(num / den);
    }
}

extern "C" void kernel_launch(void* const* d_in, const int* in_sizes, int n_in,
                              void* d_out, int out_size, void* d_ws, size_t ws_size,
                              hipStream_t stream)
{
    (void)in_sizes; (void)n_in; (void)out_size; (void)ws_size;
    const float* x   = (const float*)d_in[0];
    const float* Wq  = (const float*)d_in[1];
    const float* bq  = (const float*)d_in[2];
    const float* Wk  = (const float*)d_in[3];
    const float* bk  = (const float*)d_in[4];
    const float* Wv  = (const float*)d_in[5];
    const float* bv  = (const float*)d_in[6];
    const float* Wp  = (const float*)d_in[7];
    const float* bp  = (const float*)d_in[8];
    const float* gq  = (const float*)d_in[9];
    const float* bbq = (const float*)d_in[10];
    const float* gk  = (const float*)d_in[11];
    const float* bbk = (const float*)d_in[12];
    const float* qG1 = (const float*)d_in[13];
    const float* qG2 = (const float*)d_in[14];
    const float* kG1 = (const float*)d_in[15];
    const float* kG2 = (const float*)d_in[16];

    float* ws  = (float*)d_ws;
    float* Q   = ws;                                   // 16,777,216 f
    float* Kb  = ws + 16777216;                        // 16,777,216 f
    float* V   = ws + 2 * 16777216;                    // 16,777,216 f
    float* R3  = ws + 3 * 16777216;                    // 8,388,608 f (32 MB shared region)
    unsigned short* xb  = (unsigned short*)R3;         // bf16 x  (dead after QKV gemm)
    float* KVP = R3;                                   // then kv partials
    float* KSP = R3 + 4194304;
    unsigned short* OAb = (unsigned short*)R3;         // then bf16 attn output
    float* KV  = ws + 3 * 16777216 + 8388608;          // 131,072 f
    float* KS  = KV + 131072;                          // 2,048 f
    unsigned short* WT = (unsigned short*)(KS + 2048); // 4 * 262,144 bf16 = 2 MB
    float* out = (float*)d_out;

    hipLaunchKernelGGL(convert_x, dim3(8192), dim3(256), 0, stream, x, xb);
    hipLaunchKernelGGL(convert_wT, dim3(16, 16, 4), dim3(256), 0, stream,
                       Wq, Wk, Wv, Wp, WT);
    hipLaunchKernelGGL(gemm_mfma_qkv, dim3(256, 4, 3), dim3(256), 0, stream,
                       xb, WT, bq, bk, bv, gq, bbq, gk, bbk, Q, Kb, V);
    hipLaunchKernelGGL(sketch_p4, dim3(4096), dim3(256), 0, stream, Q, qG1, qG2);
    hipLaunchKernelGGL(sketch_p4, dim3(4096), dim3(256), 0, stream, Kb, kG1, kG2);
    hipLaunchKernelGGL(kv_partial, dim3(32, 32), dim3(256), 0, stream, Kb, V, KVP, KSP);
    hipLaunchKernelGGL(kv_reduce, dim3(32), dim3(256), 0, stream, KVP, KSP, KV, KS);
    hipLaunchKernelGGL(attn_out, dim3(32, 64), dim3(256), 0, stream, Q, KV, KS, OAb);
    hipLaunchKernelGGL(gemm_mfma_final, dim3(256, 4), dim3(256), 0, stream,
                       OAb, WT + 3 * 262144, bp, out);
}

// Round 4
// 477.545 us; speedup vs baseline: 3.3323x; 1.7722x over previous
//
#include <hip/hip_runtime.h>
#include <hip/hip_bf16.h>

// MHSA_69621419869026 — p=4 sketch linear attention, MI355X gfx950.
// Round 4: register-tiled (4x4 per thread) sketch / kv_partial / attn_out to
// fix LDS-issue-bound inner loops (3 ds_read_b32 per 2 FMA -> 6 LDS issues
// per 32 FMA). GEMMs unchanged from round 3 (bf16 MFMA 16x16x32, 128x128).
// Dims: B=4 S=8192 D=512 H=8 HD=R=64, N=B*S=32768.

#define SEQ 8192

typedef __attribute__((ext_vector_type(8))) short bf16x8;
typedef __attribute__((ext_vector_type(4))) float f32x4;

__device__ __forceinline__ unsigned short f2b(float f) {
    union { float f; unsigned int i; } v; v.f = f;
    unsigned int r = v.i + 0x7fffu + ((v.i >> 16) & 1u);   // RNE
    return (unsigned short)(r >> 16);
}

#if __has_builtin(__builtin_amdgcn_global_load_lds)
#define ASYNC_CP 1
#endif

__device__ __forceinline__ void cp16(const unsigned short* g, unsigned short* l) {
#ifdef ASYNC_CP
    __builtin_amdgcn_global_load_lds(
        (const __attribute__((address_space(1))) unsigned int*)g,
        (__attribute__((address_space(3))) unsigned int*)l, 16, 0, 0);
#endif
}

// ---------------- pre-pass: x fp32 -> bf16 (RNE) ----------------------------
__global__ __launch_bounds__(256) void convert_x(
    const float* __restrict__ x, unsigned short* __restrict__ xb)
{
    size_t i = ((size_t)blockIdx.x * 256 + threadIdx.x) * 8;
    float4 a = *(const float4*)&x[i];
    float4 b = *(const float4*)&x[i + 4];
    ushort4 o1 = { f2b(a.x), f2b(a.y), f2b(a.z), f2b(a.w) };
    ushort4 o2 = { f2b(b.x), f2b(b.y), f2b(b.z), f2b(b.w) };
    *(ushort4*)&xb[i]     = o1;
    *(ushort4*)&xb[i + 4] = o2;
}

// ---------------- pre-pass: W fp32 [k][n] -> WT bf16 [n][k] ------------------
__global__ __launch_bounds__(256) void convert_wT(
    const float* __restrict__ Wq, const float* __restrict__ Wk,
    const float* __restrict__ Wv, const float* __restrict__ Wp,
    unsigned short* __restrict__ WT)
{
    const int z = blockIdx.z;
    const float* W = (z == 0) ? Wq : (z == 1) ? Wk : (z == 2) ? Wv : Wp;
    unsigned short* O = WT + (size_t)z * 262144;
    __shared__ float t[32][33];
    const int tid = threadIdx.x;
    const int tx = tid & 31, ty = tid >> 5;
    const int k0 = blockIdx.x * 32, n0 = blockIdx.y * 32;
    #pragma unroll
    for (int i = 0; i < 4; ++i)
        t[ty + 8 * i][tx] = W[(size_t)(k0 + ty + 8 * i) * 512 + n0 + tx];
    __syncthreads();
    #pragma unroll
    for (int i = 0; i < 4; ++i)
        O[(size_t)(n0 + ty + 8 * i) * 512 + k0 + tx] = f2b(t[tx][ty + 8 * i]);
}

// ---------------- bf16 MFMA GEMM: QKV projection (unchanged) -----------------
__global__ __launch_bounds__(256) void gemm_mfma_qkv(
    const unsigned short* __restrict__ xb,
    const unsigned short* __restrict__ WT,
    const float* __restrict__ bq, const float* __restrict__ bk,
    const float* __restrict__ bvp,
    const float* __restrict__ gq, const float* __restrict__ bbq,
    const float* __restrict__ gk, const float* __restrict__ bbk,
    float* __restrict__ Q, float* __restrict__ Ko, float* __restrict__ Vo)
{
    const int z = blockIdx.z;
    const unsigned short* Wt = WT + (size_t)z * 262144;
    const float* bias = (z == 0) ? bq : (z == 1) ? bk : bvp;
    float g = 1.0f, be = 0.0f;
    if (z == 0)      { g = gq[0]; be = bbq[0]; }
    else if (z == 1) { g = gk[0]; be = bbk[0]; }
    float* C = (z == 0) ? Q : (z == 1) ? Ko : Vo;

    __shared__ __align__(16) unsigned short As[128 * 32];
    __shared__ __align__(16) unsigned short Bs[128 * 32];

    const int tid = threadIdx.x;
    const int w = tid >> 6, lane = tid & 63;
    const int n0 = blockIdx.x * 128;
    const int j0 = blockIdx.y * 128;
    const int wr = w >> 1, wc = w & 1;

    const int r0 = w * 32 + (lane >> 2);
    const int kq = (lane & 3) * 8;
    const unsigned short* gA = &xb[(size_t)(n0 + r0) * 512 + kq];
    const unsigned short* gB = &Wt[(size_t)(j0 + r0) * 512 + kq];
    unsigned short* lA = &As[(w * 32) * 32];
    unsigned short* lB = &Bs[(w * 32) * 32];

    f32x4 acc[4][4];
    #pragma unroll
    for (int i = 0; i < 4; ++i)
        #pragma unroll
        for (int j = 0; j < 4; ++j) { acc[i][j] = (f32x4){0.f, 0.f, 0.f, 0.f}; }

    for (int k0 = 0; k0 < 512; k0 += 32) {
        __syncthreads();
#ifdef ASYNC_CP
        cp16(gA + k0, lA);
        cp16(gA + 16 * 512 + k0, lA + 16 * 32);
        cp16(gB + k0, lB);
        cp16(gB + 16 * 512 + k0, lB + 16 * 32);
#else
        { uint4 v = *(const uint4*)(gA + k0);            *(uint4*)(lA + (size_t)lane * 8) = v; }
        { uint4 v = *(const uint4*)(gA + 16 * 512 + k0); *(uint4*)(lA + 16 * 32 + (size_t)lane * 8) = v; }
        { uint4 v = *(const uint4*)(gB + k0);            *(uint4*)(lB + (size_t)lane * 8) = v; }
        { uint4 v = *(const uint4*)(gB + 16 * 512 + k0); *(uint4*)(lB + 16 * 32 + (size_t)lane * 8) = v; }
#endif
        __syncthreads();

        bf16x8 af[4], bfr[4];
        #pragma unroll
        for (int i = 0; i < 4; ++i) {
            af[i]  = *(const bf16x8*)&As[(wr * 64 + i * 16 + (lane & 15)) * 32 + (lane >> 4) * 8];
            bfr[i] = *(const bf16x8*)&Bs[(wc * 64 + i * 16 + (lane & 15)) * 32 + (lane >> 4) * 8];
        }
        #pragma unroll
        for (int mi = 0; mi < 4; ++mi)
            #pragma unroll
            for (int ni = 0; ni < 4; ++ni)
                acc[mi][ni] = __builtin_amdgcn_mfma_f32_16x16x32_bf16(
                    af[mi], bfr[ni], acc[mi][ni], 0, 0, 0);
    }

    #pragma unroll
    for (int ni = 0; ni < 4; ++ni) {
        const int jcol = j0 + wc * 64 + ni * 16 + (lane & 15);
        const float bv = bias[jcol];
        const int h = jcol >> 6, hd = jcol & 63;
        #pragma unroll
        for (int mi = 0; mi < 4; ++mi) {
            #pragma unroll
            for (int r = 0; r < 4; ++r) {
                const int t = n0 + wr * 64 + mi * 16 + (lane >> 4) * 4 + r;
                const int b = t >> 13, s = t & (SEQ - 1);
                C[(((size_t)(b * 8 + h)) * SEQ + s) * 64 + hd] =
                    fmaf(g, acc[mi][ni][r] + bv, be);
            }
        }
    }
}

// ---------------- bf16 MFMA GEMM: final projection (unchanged) ---------------
__global__ __launch_bounds__(256) void gemm_mfma_final(
    const unsigned short* __restrict__ Ab,
    const unsigned short* __restrict__ WTp,
    const float* __restrict__ bias, float* __restrict__ out)
{
    __shared__ __align__(16) unsigned short As[128 * 32];
    __shared__ __align__(16) unsigned short Bs[128 * 32];

    const int tid = threadIdx.x;
    const int w = tid >> 6, lane = tid & 63;
    const int n0 = blockIdx.x * 128;
    const int j0 = blockIdx.y * 128;
    const int wr = w >> 1, wc = w & 1;

    const int r0 = w * 32 + (lane >> 2);
    const int kq = (lane & 3) * 8;
    const unsigned short* gA = &Ab[(size_t)(n0 + r0) * 512 + kq];
    const unsigned short* gB = &WTp[(size_t)(j0 + r0) * 512 + kq];
    unsigned short* lA = &As[(w * 32) * 32];
    unsigned short* lB = &Bs[(w * 32) * 32];

    f32x4 acc[4][4];
    #pragma unroll
    for (int i = 0; i < 4; ++i)
        #pragma unroll
        for (int j = 0; j < 4; ++j) { acc[i][j] = (f32x4){0.f, 0.f, 0.f, 0.f}; }

    for (int k0 = 0; k0 < 512; k0 += 32) {
        __syncthreads();
#ifdef ASYNC_CP
        cp16(gA + k0, lA);
        cp16(gA + 16 * 512 + k0, lA + 16 * 32);
        cp16(gB + k0, lB);
        cp16(gB + 16 * 512 + k0, lB + 16 * 32);
#else
        { uint4 v = *(const uint4*)(gA + k0);            *(uint4*)(lA + (size_t)lane * 8) = v; }
        { uint4 v = *(const uint4*)(gA + 16 * 512 + k0); *(uint4*)(lA + 16 * 32 + (size_t)lane * 8) = v; }
        { uint4 v = *(const uint4*)(gB + k0);            *(uint4*)(lB + (size_t)lane * 8) = v; }
        { uint4 v = *(const uint4*)(gB + 16 * 512 + k0); *(uint4*)(lB + 16 * 32 + (size_t)lane * 8) = v; }
#endif
        __syncthreads();

        bf16x8 af[4], bfr[4];
        #pragma unroll
        for (int i = 0; i < 4; ++i) {
            af[i]  = *(const bf16x8*)&As[(wr * 64 + i * 16 + (lane & 15)) * 32 + (lane >> 4) * 8];
            bfr[i] = *(const bf16x8*)&Bs[(wc * 64 + i * 16 + (lane & 15)) * 32 + (lane >> 4) * 8];
        }
        #pragma unroll
        for (int mi = 0; mi < 4; ++mi)
            #pragma unroll
            for (int ni = 0; ni < 4; ++ni)
                acc[mi][ni] = __builtin_amdgcn_mfma_f32_16x16x32_bf16(
                    af[mi], bfr[ni], acc[mi][ni], 0, 0, 0);
    }

    #pragma unroll
    for (int ni = 0; ni < 4; ++ni) {
        const int jcol = j0 + wc * 64 + ni * 16 + (lane & 15);
        const float bv = bias[jcol];
        #pragma unroll
        for (int mi = 0; mi < 4; ++mi) {
            #pragma unroll
            for (int r = 0; r < 4; ++r) {
                const int t = n0 + wr * 64 + mi * 16 + (lane >> 4) * 4 + r;
                out[(size_t)t * 512 + jcol] = acc[mi][ni][r] + bv;
            }
        }
    }
}

// ---------------- sketch: phi = (0.125*(z@G1)*(z@G2))^2, in place ------------
// Register-tiled: 4096 blocks x 256 thr; block = 64 rows; thread = 4x4 tile.
// Inner i: 4 broadcast b32 (z) + 2 b128 (G cols) per 32 FMA.
__global__ __launch_bounds__(256) void sketch_p4(
    float* __restrict__ Z,
    const float* __restrict__ G1, const float* __restrict__ G2)
{
    __shared__ float G1s[64][68];    // stride 68: float4-stageable, b128 reads
    __shared__ float G2s[64][68];
    __shared__ float zs[64][65];     // stride 65: conflict-free column reads
    const int tid = threadIdx.x;
    const int tx = tid & 15, ty = tid >> 4;
    const size_t base = (size_t)blockIdx.x * 4096;   // 64 rows * 64
    {
        const int r = tid >> 4, c4 = (tid & 15) * 4;
        #pragma unroll
        for (int it = 0; it < 4; ++it) {
            float4 g1 = *(const float4*)&G1[(r + 16 * it) * 64 + c4];
            float4 g2 = *(const float4*)&G2[(r + 16 * it) * 64 + c4];
            float4 zv = *(const float4*)&Z[base + (size_t)(r + 16 * it) * 64 + c4];
            *(float4*)&G1s[r + 16 * it][c4] = g1;
            *(float4*)&G2s[r + 16 * it][c4] = g2;
            zs[r + 16 * it][c4 + 0] = zv.x; zs[r + 16 * it][c4 + 1] = zv.y;
            zs[r + 16 * it][c4 + 2] = zv.z; zs[r + 16 * it][c4 + 3] = zv.w;
        }
    }
    __syncthreads();
    const int r0 = ty * 4, c0 = tx * 4;
    float u[4][4] = {}, w[4][4] = {};
    #pragma unroll 4
    for (int i = 0; i < 64; ++i) {
        float zr[4] = { zs[r0][i], zs[r0 + 1][i], zs[r0 + 2][i], zs[r0 + 3][i] };
        float4 g1 = *(const float4*)&G1s[i][c0];
        float4 g2 = *(const float4*)&G2s[i][c0];
        float g1a[4] = { g1.x, g1.y, g1.z, g1.w };
        float g2a[4] = { g2.x, g2.y, g2.z, g2.w };
        #pragma unroll
        for (int a = 0; a < 4; ++a)
            #pragma unroll
            for (int bb = 0; bb < 4; ++bb) {
                u[a][bb] = fmaf(zr[a], g1a[bb], u[a][bb]);
                w[a][bb] = fmaf(zr[a], g2a[bb], w[a][bb]);
            }
    }
    #pragma unroll
    for (int a = 0; a < 4; ++a) {
        float4 o;
        float h0 = 0.125f * u[a][0] * w[a][0]; o.x = h0 * h0;
        float h1 = 0.125f * u[a][1] * w[a][1]; o.y = h1 * h1;
        float h2 = 0.125f * u[a][2] * w[a][2]; o.z = h2 * h2;
        float h3 = 0.125f * u[a][3] * w[a][3]; o.w = h3 * h3;
        *(float4*)&Z[base + (size_t)(r0 + a) * 64 + c0] = o;
    }
}

// ---------------- kv = phi_k^T @ v, ksum (split-S partials), 4x4 tiled -------
// grid (32 bh, 32 chunks of 256 s). thread = 4 R-rows x 4 d-cols.
__global__ __launch_bounds__(256) void kv_partial(
    const float* __restrict__ PHIK, const float* __restrict__ V,
    float* __restrict__ KVP, float* __restrict__ KSP)
{
    const int bh = blockIdx.x, ch = blockIdx.y;
    const float* phik = PHIK + ((size_t)bh * SEQ + ch * 256) * 64;
    const float* v    = V    + ((size_t)bh * SEQ + ch * 256) * 64;
    __shared__ float ps[64][68];
    __shared__ float vs[64][68];
    const int tid = threadIdx.x;
    const int tx = tid & 15, ty = tid >> 4;
    const int r0 = ty * 4, c0 = tx * 4;
    float acc[4][4] = {};
    float ks[4] = {};
    for (int sub = 0; sub < 4; ++sub) {
        __syncthreads();
        {
            const int r = tid >> 4, c4 = (tid & 15) * 4;
            #pragma unroll
            for (int it = 0; it < 4; ++it) {
                float4 p = *(const float4*)&phik[(size_t)(sub * 64 + r + 16 * it) * 64 + c4];
                float4 vv = *(const float4*)&v[(size_t)(sub * 64 + r + 16 * it) * 64 + c4];
                *(float4*)&ps[r + 16 * it][c4] = p;
                *(float4*)&vs[r + 16 * it][c4] = vv;
            }
        }
        __syncthreads();
        #pragma unroll 4
        for (int s = 0; s < 64; ++s) {
            float4 p4 = *(const float4*)&ps[s][r0];
            float4 v4 = *(const float4*)&vs[s][c0];
            float pa[4] = { p4.x, p4.y, p4.z, p4.w };
            float va[4] = { v4.x, v4.y, v4.z, v4.w };
            #pragma unroll
            for (int a = 0; a < 4; ++a) {
                ks[a] += pa[a];
                #pragma unroll
                for (int bb = 0; bb < 4; ++bb)
                    acc[a][bb] = fmaf(pa[a], va[bb], acc[a][bb]);
            }
        }
    }
    #pragma unroll
    for (int a = 0; a < 4; ++a) {
        float4 o = { acc[a][0], acc[a][1], acc[a][2], acc[a][3] };
        *(float4*)&KVP[((size_t)(bh * 32 + ch) * 64 + r0 + a) * 64 + c0] = o;
    }
    if (tx == 0) {
        #pragma unroll
        for (int a = 0; a < 4; ++a)
            KSP[(bh * 32 + ch) * 64 + r0 + a] = ks[a];
    }
}

__global__ __launch_bounds__(256) void kv_reduce(
    const float* __restrict__ KVP, const float* __restrict__ KSP,
    float* __restrict__ KV, float* __restrict__ KS)
{
    const int bh = blockIdx.x, tid = threadIdx.x;
    for (int e = tid; e < 4096; e += 256) {
        float s = 0.f;
        for (int c = 0; c < 32; ++c) s += KVP[(size_t)(bh * 32 + c) * 4096 + e];
        KV[(size_t)bh * 4096 + e] = s;
    }
    if (tid < 64) {
        float s = 0.f;
        for (int c = 0; c < 32; ++c) s += KSP[(bh * 32 + c) * 64 + tid];
        KS[bh * 64 + tid] = s;
    }
}

// ---------------- out_attn = (phi_q@kv)/(phi_q@ksum+eps) -> bf16, 4x4 tiled --
// grid (32 bh, 128 tiles of 64 rows). thread = 4 rows x 4 hd-cols.
__global__ __launch_bounds__(256) void attn_out(
    const float* __restrict__ PHIQ, const float* __restrict__ KV,
    const float* __restrict__ KS, unsigned short* __restrict__ OAb)
{
    const int bh = blockIdx.x;
    const int b = bh >> 3, h = bh & 7;
    __shared__ float kvs[64][68];
    __shared__ float pqs[64][65];
    __shared__ float kss[64];
    const int tid = threadIdx.x;
    const int tx = tid & 15, ty = tid >> 4;
    const int s0 = blockIdx.y * 64;
    {
        const int r = tid >> 4, c4 = (tid & 15) * 4;
        #pragma unroll
        for (int it = 0; it < 4; ++it) {
            float4 kvv = *(const float4*)&KV[(size_t)bh * 4096 + (size_t)(r + 16 * it) * 64 + c4];
            float4 pq  = *(const float4*)&PHIQ[((size_t)bh * SEQ + s0 + r + 16 * it) * 64 + c4];
            *(float4*)&kvs[r + 16 * it][c4] = kvv;
            pqs[r + 16 * it][c4 + 0] = pq.x; pqs[r + 16 * it][c4 + 1] = pq.y;
            pqs[r + 16 * it][c4 + 2] = pq.z; pqs[r + 16 * it][c4 + 3] = pq.w;
        }
        if (tid < 64) kss[tid] = KS[bh * 64 + tid];
    }
    __syncthreads();
    const int r0 = ty * 4, c0 = tx * 4;
    float num[4][4] = {};
    float den[4] = { 1e-6f, 1e-6f, 1e-6f, 1e-6f };
    #pragma unroll 4
    for (int i = 0; i < 64; ++i) {
        float pr[4] = { pqs[r0][i], pqs[r0 + 1][i], pqs[r0 + 2][i], pqs[r0 + 3][i] };
        float4 kv4 = *(const float4*)&kvs[i][c0];
        float kva[4] = { kv4.x, kv4.y, kv4.z, kv4.w };
        float ksv = kss[i];
        #pragma unroll
        for (int a = 0; a < 4; ++a) {
            den[a] = fmaf(pr[a], ksv, den[a]);
            #pragma unroll
            for (int bb = 0; bb < 4; ++bb)
                num[a][bb] = fmaf(pr[a], kva[bb], num[a][bb]);
        }
    }
    #pragma unroll
    for (int a = 0; a < 4; ++a) {
        const float inv = 1.0f / den[a];
        ushort4 o = { f2b(num[a][0] * inv), f2b(num[a][1] * inv),
                      f2b(num[a][2] * inv), f2b(num[a][3] * inv) };
        const int s = s0 + r0 + a;
        *(ushort4*)&OAb[((size_t)(b * SEQ + s)) * 512 + h * 64 + c0] = o;
    }
}

extern "C" void kernel_launch(void* const* d_in, const int* in_sizes, int n_in,
                              void* d_out, int out_size, void* d_ws, size_t ws_size,
                              hipStream_t stream)
{
    (void)in_sizes; (void)n_in; (void)out_size; (void)ws_size;
    const float* x   = (const float*)d_in[0];
    const float* Wq  = (const float*)d_in[1];
    const float* bq  = (const float*)d_in[2];
    const float* Wk  = (const float*)d_in[3];
    const float* bk  = (const float*)d_in[4];
    const float* Wv  = (const float*)d_in[5];
    const float* bv  = (const float*)d_in[6];
    const float* Wp  = (const float*)d_in[7];
    const float* bp  = (const float*)d_in[8];
    const float* gq  = (const float*)d_in[9];
    const float* bbq = (const float*)d_in[10];
    const float* gk  = (const float*)d_in[11];
    const float* bbk = (const float*)d_in[12];
    const float* qG1 = (const float*)d_in[13];
    const float* qG2 = (const float*)d_in[14];
    const float* kG1 = (const float*)d_in[15];
    const float* kG2 = (const float*)d_in[16];

    float* ws  = (float*)d_ws;
    float* Q   = ws;                                   // 16,777,216 f
    float* Kb  = ws + 16777216;                        // 16,777,216 f
    float* V   = ws + 2 * 16777216;                    // 16,777,216 f
    float* R3  = ws + 3 * 16777216;                    // 8,388,608 f shared region
    unsigned short* xb  = (unsigned short*)R3;
    float* KVP = R3;
    float* KSP = R3 + 4194304;
    unsigned short* OAb = (unsigned short*)R3;
    float* KV  = ws + 3 * 16777216 + 8388608;          // 131,072 f
    float* KS  = KV + 131072;                          // 2,048 f
    unsigned short* WT = (unsigned short*)(KS + 2048); // 2 MB
    float* out = (float*)d_out;

    hipLaunchKernelGGL(convert_x, dim3(8192), dim3(256), 0, stream, x, xb);
    hipLaunchKernelGGL(convert_wT, dim3(16, 16, 4), dim3(256), 0, stream,
                       Wq, Wk, Wv, Wp, WT);
    hipLaunchKernelGGL(gemm_mfma_qkv, dim3(256, 4, 3), dim3(256), 0, stream,
                       xb, WT, bq, bk, bv, gq, bbq, gk, bbk, Q, Kb, V);
    hipLaunchKernelGGL(sketch_p4, dim3(4096), dim3(256), 0, stream, Q, qG1, qG2);
    hipLaunchKernelGGL(sketch_p4, dim3(4096), dim3(256), 0, stream, Kb, kG1, kG2);
    hipLaunchKernelGGL(kv_partial, dim3(32, 32), dim3(256), 0, stream, Kb, V, KVP, KSP);
    hipLaunchKernelGGL(kv_reduce, dim3(32), dim3(256), 0, stream, KVP, KSP, KV, KS);
    hipLaunchKernelGGL(attn_out, dim3(32, 128), dim3(256), 0, stream, Q, KV, KS, OAb);
    hipLaunchKernelGGL(gemm_mfma_final, dim3(256, 4), dim3(256), 0, stream,
                       OAb, WT + 3 * 262144, bp, out);
}